// Round 8
// baseline (210.846 us; speedup 1.0000x reference)
//
#include <hip/hip_runtime.h>
#include <math.h>

#define D    256   // input feature dim
#define BLK  64    // threads per block == samples per block == ONE wave
#define RPC  8     // rows (samples) per chunk
#define NCH  (BLK/RPC)  // 8 chunks

struct C2 { float x, y; };

__device__ __forceinline__ float4 shfl_xor4(float4 a, int m) {
  float4 r;
  r.x = __shfl_xor(a.x, m); r.y = __shfl_xor(a.y, m);
  r.z = __shfl_xor(a.z, m); r.w = __shfl_xor(a.w, m);
  return r;
}
__device__ __forceinline__ float4 add4(float4 a, float4 b) {
  return make_float4(a.x+b.x, a.y+b.y, a.z+b.z, a.w+b.w);
}

// RY(t): [[c,-s],[s,c]] with c=cos(t/2), s=sin(t/2), applied on qubit mask m
__device__ __forceinline__ void gate_ry(C2 st[16], const int m, float c, float s) {
#pragma unroll
  for (int i = 0; i < 16; ++i) {
    if (i & m) continue;
    const int i1 = i | m;
    C2 a0 = st[i], a1 = st[i1];
    st[i].x  = c*a0.x - s*a1.x;  st[i].y  = c*a0.y - s*a1.y;
    st[i1].x = s*a0.x + c*a1.x;  st[i1].y = s*a0.y + c*a1.y;
  }
}

// RZ(t): diag(e^{-it/2}, e^{+it/2}); c=cos(t/2), s=sin(t/2)
__device__ __forceinline__ void gate_rz(C2 st[16], const int m, float c, float s) {
#pragma unroll
  for (int i = 0; i < 16; ++i) {
    C2 a = st[i];
    if (i & m) { st[i].x = a.x*c - a.y*s; st[i].y = a.y*c + a.x*s; }
    else       { st[i].x = a.x*c + a.y*s; st[i].y = a.y*c - a.x*s; }
  }
}

// Row-contiguous streaming: every global_load_dwordx4 reads ONE full 1KB row
// (64 lanes x 16B contiguous); block walks its 64KB strictly sequentially.
// (r3/r6 lesson: column-chunked 128B-per-1KB strided walk ran at 2.1 TB/s
// regardless of occupancy -> DRAM row-buffer thrash, not latency, was the cap.)
// Projection uses NO LDS: lane l owns cols 4l..4l+3 (w fragment in 16 VGPRs),
// full dots come from a 6-stage shfl_xor reduction with row splitting.
__global__ __launch_bounds__(BLK, 4) void qhead_kernel(
    const float4* __restrict__ x4,
    const float*  __restrict__ w_proj,
    const float*  __restrict__ b_proj,
    const float*  __restrict__ qw,      // [2,4,2]
    const float*  __restrict__ w_h,     // [16,4]
    const float*  __restrict__ b_h,     // [16]
    const float*  __restrict__ w_out,   // [10,16]
    const float*  __restrict__ b_out,   // [10]
    float*        __restrict__ out)     // [B,10]
{
  __shared__ float outS[BLK * 11];    // output staging (stride 11: 2-way banks)

  const int tid = threadIdx.x;
  const long s0 = (long)blockIdx.x * BLK;
  const float4* xrow = x4 + s0 * (D / 4);   // 64 float4 per row

  // per-lane w fragment: wj[j] = w_proj[j][4*tid .. 4*tid+3] (1KB contiguous per j)
  float4 wj[4];
#pragma unroll
  for (int j = 0; j < 4; ++j)
    wj[j] = *(const float4*)(w_proj + j * D + 4 * tid);

  // prologue: chunk 0 rows (instr i reads row i, 1KB contiguous)
  float4 v[8];
#pragma unroll
  for (int i = 0; i < 8; ++i) v[i] = xrow[(long)i * (D/4) + tid];

  const int b5 = (tid >> 5) & 1, b4 = (tid >> 4) & 1, b3 = (tid >> 3) & 1;
  const int csel = tid & 7;
  float4 acc = make_float4(0.f, 0.f, 0.f, 0.f);

#pragma unroll 1                      // keep rolled: bounded live set (r2 lesson)
  for (int c = 0; c < NCH; ++c) {
    // partial dots: p[i].j = <v[i], wj[j]>  (128 FMA)
    float4 p[8];
#pragma unroll
    for (int i = 0; i < 8; ++i) {
      p[i].x = v[i].x*wj[0].x + v[i].y*wj[0].y + v[i].z*wj[0].z + v[i].w*wj[0].w;
      p[i].y = v[i].x*wj[1].x + v[i].y*wj[1].y + v[i].z*wj[1].z + v[i].w*wj[1].w;
      p[i].z = v[i].x*wj[2].x + v[i].y*wj[2].y + v[i].z*wj[2].z + v[i].w*wj[2].w;
      p[i].w = v[i].x*wj[3].x + v[i].y*wj[3].y + v[i].z*wj[3].z + v[i].w*wj[3].w;
    }
    // issue next chunk's row loads (sequential 8KB; hides under reduction)
    if (c + 1 < NCH) {
#pragma unroll
      for (int i = 0; i < 8; ++i)
        v[i] = xrow[((long)(c + 1) * RPC + i) * (D/4) + tid];
    }
    // 64-lane reduction with row splitting:
    // stage xor32: half keeps rows 0-3, half rows 4-7
    float4 q[4];
#pragma unroll
    for (int i = 0; i < 4; ++i) {
      float4 send = b5 ? p[i] : p[i + 4];
      float4 keep = b5 ? p[i + 4] : p[i];
      q[i] = add4(keep, shfl_xor4(send, 32));
    }
    float4 u[2];
#pragma unroll
    for (int i = 0; i < 2; ++i) {
      float4 send = b4 ? u[0] : u[0];  // placeholder overwritten below
      (void)send;
      float4 s2 = b4 ? q[i] : q[i + 2];
      float4 k2 = b4 ? q[i + 2] : q[i];
      u[i] = add4(k2, shfl_xor4(s2, 16));
    }
    float4 t;
    {
      float4 s3 = b3 ? u[0] : u[1];
      float4 k3 = b3 ? u[1] : u[0];
      t = add4(k3, shfl_xor4(s3, 8));
    }
    // now t = row (tid>>3)'s sums over lane-bits 3-5; finish bits 0-2
    t = add4(t, shfl_xor4(t, 4));
    t = add4(t, shfl_xor4(t, 2));
    t = add4(t, shfl_xor4(t, 1));
    // lane keeps chunk (tid&7): final sample = 8*(tid&7) + (tid>>3)
    if (csel == c) acc = t;
  }

  const float PI_F = 3.14159265358979f;
  float ang[4];
  ang[0] = tanhf(acc.x + b_proj[0]) * PI_F;
  ang[1] = tanhf(acc.y + b_proj[1]) * PI_F;
  ang[2] = tanhf(acc.z + b_proj[2]) * PI_F;
  ang[3] = tanhf(acc.w + b_proj[3]) * PI_F;

  // ---- 4-qubit statevector sim, fully in registers (static indices only) ----
  float ch[4], sh[4], cf[4], sf[4];
#pragma unroll
  for (int w = 0; w < 4; ++w) {
    __sincosf(0.5f * ang[w], &sh[w], &ch[w]);  // sin/cos(a/2): RY(a) and RZ(a)
    __sincosf(ang[w], &sf[w], &cf[w]);         // sin/cos(a):   RZ(2a)
  }

  C2 st[16];
#pragma unroll
  for (int i = 0; i < 16; ++i) { st[i].x = 0.f; st[i].y = 0.f; }
  st[0].x = 1.f;

#pragma unroll
  for (int layer = 0; layer < 2; ++layer) {
#pragma unroll
    for (int w = 0; w < 4; ++w) {     // data-dependent gates
      gate_ry(st, 8 >> w, ch[w], sh[w]);
      if (layer == 0) gate_rz(st, 8 >> w, ch[w], sh[w]);   // t = a
      else            gate_rz(st, 8 >> w, cf[w], sf[w]);   // t = 2a
    }
#pragma unroll
    for (int w = 0; w < 4; ++w) {     // trained gates (uniform scalar loads)
      float cw, sw, cz, sz;
      __sincosf(0.5f * qw[(layer * 4 + w) * 2 + 0], &sw, &cw);
      __sincosf(0.5f * qw[(layer * 4 + w) * 2 + 1], &sz, &cz);
      gate_ry(st, 8 >> w, cw, sw);
      gate_rz(st, 8 >> w, cz, sz);
    }
#pragma unroll
    for (int w = 0; w < 3; ++w) {     // CNOT chain: pure register swaps
      const int mc = 8 >> w, mt = 4 >> w;
#pragma unroll
      for (int i = 0; i < 16; ++i) {
        if ((i & mc) && !(i & mt)) {
          C2 t2 = st[i]; st[i] = st[i | mt]; st[i | mt] = t2;
        }
      }
    }
  }

  // ---- <Z_w> expvals ----
  float z[4] = {0.f, 0.f, 0.f, 0.f};
#pragma unroll
  for (int i = 0; i < 16; ++i) {
    const float p = st[i].x * st[i].x + st[i].y * st[i].y;
#pragma unroll
    for (int w = 0; w < 4; ++w) z[w] += (i & (8 >> w)) ? -p : p;
  }

  // ---- MLP head (weights via uniform scalar loads) ----
  float outv[10];
  {
    float h[16];
#pragma unroll
    for (int j = 0; j < 16; ++j) {
      float a = b_h[j];
#pragma unroll
      for (int w = 0; w < 4; ++w) a += w_h[j * 4 + w] * z[w];
      h[j] = fmaxf(a, 0.f);
    }
#pragma unroll
    for (int o = 0; o < 10; ++o) {
      float a = b_out[o];
#pragma unroll
      for (int j = 0; j < 16; ++j) a += w_out[o * 16 + j] * h[j];
      outv[o] = a;
    }
  }

  // ---- coalesced output via LDS staging (lane's sample = σ(tid)) ----
  const int smp = 8 * csel + (tid >> 3);   // σ: bijection on 0..63
#pragma unroll
  for (int o = 0; o < 10; ++o) outS[smp * 11 + o] = outv[o];
  __syncthreads();                    // 1-wave block: waitcnt only
  float* og = out + (long)blockIdx.x * (BLK * 10);
#pragma unroll
  for (int i = 0; i < 10; ++i) {      // 640 contiguous floats, 64/iter
    const int j = i * BLK + tid;
    og[j] = outS[(j / 10) * 11 + (j % 10)];
  }
}

extern "C" void kernel_launch(void* const* d_in, const int* in_sizes, int n_in,
                              void* d_out, int out_size, void* d_ws, size_t ws_size,
                              hipStream_t stream) {
  const int B = in_sizes[0] / D;      // 131072
  dim3 grid(B / BLK), block(BLK);
  qhead_kernel<<<grid, block, 0, stream>>>(
      (const float4*)d_in[0],
      (const float*)d_in[1], (const float*)d_in[2], (const float*)d_in[3],
      (const float*)d_in[4], (const float*)d_in[5], (const float*)d_in[6],
      (const float*)d_in[7], (float*)d_out);
}

// Round 11
// 210.165 us; speedup vs baseline: 1.0032x; 1.0032x over previous
//
#include <hip/hip_runtime.h>
#include <math.h>

#define D    256   // input feature dim
#define BLK  64    // threads per block == ONE wave
#define SPB  32    // samples per block (4096 blocks -> 16 blocks/CU demanded)
#define RPC  8     // rows (samples) per chunk = 8 row-loads per burst
#define NCH  (SPB/RPC)  // 4 chunks

struct C2 { float x, y; };

__device__ __forceinline__ float4 shfl_xor4(float4 a, int m) {
  float4 r;
  r.x = __shfl_xor(a.x, m); r.y = __shfl_xor(a.y, m);
  r.z = __shfl_xor(a.z, m); r.w = __shfl_xor(a.w, m);
  return r;
}
__device__ __forceinline__ float4 add4(float4 a, float4 b) {
  return make_float4(a.x+b.x, a.y+b.y, a.z+b.z, a.w+b.w);
}

// RY(t): [[c,-s],[s,c]] with c=cos(t/2), s=sin(t/2), applied on qubit mask m
__device__ __forceinline__ void gate_ry(C2 st[16], const int m, float c, float s) {
#pragma unroll
  for (int i = 0; i < 16; ++i) {
    if (i & m) continue;
    const int i1 = i | m;
    C2 a0 = st[i], a1 = st[i1];
    st[i].x  = c*a0.x - s*a1.x;  st[i].y  = c*a0.y - s*a1.y;
    st[i1].x = s*a0.x + c*a1.x;  st[i1].y = s*a0.y + c*a1.y;
  }
}

// RZ(t): diag(e^{-it/2}, e^{+it/2}); c=cos(t/2), s=sin(t/2)
__device__ __forceinline__ void gate_rz(C2 st[16], const int m, float c, float s) {
#pragma unroll
  for (int i = 0; i < 16; ++i) {
    C2 a = st[i];
    if (i & m) { st[i].x = a.x*c - a.y*s; st[i].y = a.y*c + a.x*s; }
    else       { st[i].x = a.x*c + a.y*s; st[i].y = a.y*c - a.x*s; }
  }
}

// One projection phase: consume batch V (8 rows of chunk c), issue chunk
// (c+2)'s 8 row-loads into V (keeps OTHER batch outstanding -> compiler
// waits vmcnt(8), never drain-to-zero: r3/r6/r8 all tied at 2.1 TB/s on
// the burst-then-drain cadence regardless of address pattern).
#define PHASE(V, c)                                                          \
  {                                                                          \
    float4 p[8];                                                             \
    _Pragma("unroll")                                                        \
    for (int i = 0; i < 8; ++i) {                                            \
      p[i].x = V[i].x*wj[0].x + V[i].y*wj[0].y + V[i].z*wj[0].z + V[i].w*wj[0].w; \
      p[i].y = V[i].x*wj[1].x + V[i].y*wj[1].y + V[i].z*wj[1].z + V[i].w*wj[1].w; \
      p[i].z = V[i].x*wj[2].x + V[i].y*wj[2].y + V[i].z*wj[2].z + V[i].w*wj[2].w; \
      p[i].w = V[i].x*wj[3].x + V[i].y*wj[3].y + V[i].z*wj[3].z + V[i].w*wj[3].w; \
    }                                                                        \
    if ((c) + 2 < NCH) {                                                     \
      _Pragma("unroll")                                                      \
      for (int i = 0; i < 8; ++i)                                            \
        V[i] = xrow[((long)((c) + 2) * RPC + i) * (D/4) + tid];              \
    }                                                                        \
    float4 q[4];                                                             \
    _Pragma("unroll")                                                        \
    for (int i = 0; i < 4; ++i) {                                            \
      float4 snd = b5 ? p[i] : p[i + 4];                                     \
      float4 kp  = b5 ? p[i + 4] : p[i];                                     \
      q[i] = add4(kp, shfl_xor4(snd, 32));                                   \
    }                                                                        \
    float4 u[2];                                                             \
    _Pragma("unroll")                                                        \
    for (int i = 0; i < 2; ++i) {                                            \
      float4 snd = b4 ? q[i] : q[i + 2];                                     \
      float4 kp  = b4 ? q[i + 2] : q[i];                                     \
      u[i] = add4(kp, shfl_xor4(snd, 16));                                   \
    }                                                                        \
    float4 t;                                                                \
    {                                                                        \
      float4 snd = b3 ? u[0] : u[1];                                         \
      float4 kp  = b3 ? u[1] : u[0];                                         \
      t = add4(kp, shfl_xor4(snd, 8));                                       \
    }                                                                        \
    t = add4(t, shfl_xor4(t, 4));                                            \
    t = add4(t, shfl_xor4(t, 2));                                            \
    t = add4(t, shfl_xor4(t, 1));                                            \
    if (csel == (c)) acc = t;                                                \
  }

// (64,3): VGPR cap ~170 (live ~150 with two 8xfloat4 buffers; no spill),
// 12 waves/CU resident. 4096 blocks = 16/CU demanded.
__global__ __launch_bounds__(BLK, 3) void qhead_kernel(
    const float4* __restrict__ x4,
    const float*  __restrict__ w_proj,
    const float*  __restrict__ b_proj,
    const float*  __restrict__ qw,      // [2,4,2]
    const float*  __restrict__ w_h,     // [16,4]
    const float*  __restrict__ b_h,     // [16]
    const float*  __restrict__ w_out,   // [10,16]
    const float*  __restrict__ b_out,   // [10]
    float*        __restrict__ out)     // [B,10]
{
  __shared__ float outS[SPB * 11];    // output staging (stride 11)

  const int tid = threadIdx.x;
  const long s0 = (long)blockIdx.x * SPB;
  const float4* xrow = x4 + s0 * (D / 4);   // 64 float4 per 1KB row

  // per-lane w fragment: wj[j] = w_proj[j][4*tid .. 4*tid+3]
  float4 wj[4];
#pragma unroll
  for (int j = 0; j < 4; ++j)
    wj[j] = *(const float4*)(w_proj + j * D + 4 * tid);

  const int b5 = (tid >> 5) & 1, b4 = (tid >> 4) & 1, b3 = (tid >> 3) & 1;
  const int csel = tid & 3;           // chunk this lane captures
  float4 acc = make_float4(0.f, 0.f, 0.f, 0.f);

  // prologue: 2-deep prefetch (16 loads outstanding)
  float4 vA[8], vB[8];
#pragma unroll
  for (int i = 0; i < 8; ++i) vA[i] = xrow[(long)i * (D/4) + tid];
#pragma unroll
  for (int i = 0; i < 8; ++i) vB[i] = xrow[(long)(RPC + i) * (D/4) + tid];

#pragma unroll 1                      // rolled: bounded live set (r2 lesson)
  for (int cc = 0; cc < NCH; cc += 2) {
    PHASE(vA, cc);                    // waits vA only (vB stays in flight)
    PHASE(vB, cc + 1);
  }

  const float PI_F = 3.14159265358979f;
  float ang[4];
  ang[0] = tanhf(acc.x + b_proj[0]) * PI_F;
  ang[1] = tanhf(acc.y + b_proj[1]) * PI_F;
  ang[2] = tanhf(acc.z + b_proj[2]) * PI_F;
  ang[3] = tanhf(acc.w + b_proj[3]) * PI_F;

  // ---- 4-qubit statevector sim, fully in registers (static indices only) ----
  float ch[4], sh[4], cf[4], sf[4];
#pragma unroll
  for (int w = 0; w < 4; ++w) {
    __sincosf(0.5f * ang[w], &sh[w], &ch[w]);  // sin/cos(a/2): RY(a) and RZ(a)
    __sincosf(ang[w], &sf[w], &cf[w]);         // sin/cos(a):   RZ(2a)
  }

  C2 st[16];
#pragma unroll
  for (int i = 0; i < 16; ++i) { st[i].x = 0.f; st[i].y = 0.f; }
  st[0].x = 1.f;

#pragma unroll
  for (int layer = 0; layer < 2; ++layer) {
#pragma unroll
    for (int w = 0; w < 4; ++w) {     // data-dependent gates
      gate_ry(st, 8 >> w, ch[w], sh[w]);
      if (layer == 0) gate_rz(st, 8 >> w, ch[w], sh[w]);   // t = a
      else            gate_rz(st, 8 >> w, cf[w], sf[w]);   // t = 2a
    }
#pragma unroll
    for (int w = 0; w < 4; ++w) {     // trained gates (uniform scalar loads)
      float cw, sw, cz, sz;
      __sincosf(0.5f * qw[(layer * 4 + w) * 2 + 0], &sw, &cw);
      __sincosf(0.5f * qw[(layer * 4 + w) * 2 + 1], &sz, &cz);
      gate_ry(st, 8 >> w, cw, sw);
      gate_rz(st, 8 >> w, cz, sz);
    }
#pragma unroll
    for (int w = 0; w < 3; ++w) {     // CNOT chain: pure register swaps
      const int mc = 8 >> w, mt = 4 >> w;
#pragma unroll
      for (int i = 0; i < 16; ++i) {
        if ((i & mc) && !(i & mt)) {
          C2 t2 = st[i]; st[i] = st[i | mt]; st[i | mt] = t2;
        }
      }
    }
  }

  // ---- <Z_w> expvals ----
  float z[4] = {0.f, 0.f, 0.f, 0.f};
#pragma unroll
  for (int i = 0; i < 16; ++i) {
    const float p = st[i].x * st[i].x + st[i].y * st[i].y;
#pragma unroll
    for (int w = 0; w < 4; ++w) z[w] += (i & (8 >> w)) ? -p : p;
  }

  // ---- MLP head (weights via uniform scalar loads) ----
  float outv[10];
  {
    float h[16];
#pragma unroll
    for (int j = 0; j < 16; ++j) {
      float a = b_h[j];
#pragma unroll
      for (int w = 0; w < 4; ++w) a += w_h[j * 4 + w] * z[w];
      h[j] = fmaxf(a, 0.f);
    }
#pragma unroll
    for (int o = 0; o < 10; ++o) {
      float a = b_out[o];
#pragma unroll
      for (int j = 0; j < 16; ++j) a += w_out[o * 16 + j] * h[j];
      outv[o] = a;
    }
  }

  // ---- output staging: lane's sample = 8*(tid&3)+(tid>>3); lanes tid and
  // tid^4 are duplicates and write identical values to the same slot ----
  const int smp = 8 * csel + (tid >> 3);   // 0..31
#pragma unroll
  for (int o = 0; o < 10; ++o) outS[smp * 11 + o] = outv[o];
  __syncthreads();                    // 1-wave block: waitcnt only
  float* og = out + (long)blockIdx.x * (SPB * 10);
#pragma unroll
  for (int i = 0; i < 5; ++i) {       // 320 contiguous floats, 64/iter
    const int j = i * BLK + tid;
    og[j] = outS[(j / 10) * 11 + (j % 10)];
  }
}

extern "C" void kernel_launch(void* const* d_in, const int* in_sizes, int n_in,
                              void* d_out, int out_size, void* d_ws, size_t ws_size,
                              hipStream_t stream) {
  const int B = in_sizes[0] / D;      // 131072
  dim3 grid(B / SPB), block(BLK);     // 4096 blocks
  qhead_kernel<<<grid, block, 0, stream>>>(
      (const float4*)d_in[0],
      (const float*)d_in[1], (const float*)d_in[2], (const float*)d_in[3],
      (const float*)d_in[4], (const float*)d_in[5], (const float*)d_in[6],
      (const float*)d_in[7], (float*)d_out);
}